// Round 5
// baseline (81.142 us; speedup 1.0000x reference)
//
#include <hip/hip_runtime.h>
#include <hip/hip_bf16.h>
#include <cstdint>

#define MAX_NORM (1.0f - 1e-5f)
#define LN2 0.69314718056f

typedef __attribute__((ext_vector_type(8))) short bf16x8;
typedef __attribute__((ext_vector_type(4))) float f32x4;

__device__ __forceinline__ unsigned short f2bf(float f) {
  union { float f; unsigned int u; } c; c.f = f;
  unsigned int r = c.u + 0x7fffu + ((c.u >> 16) & 1u);
  return (unsigned short)(r >> 16);
}

__device__ __forceinline__ void gld16(const unsigned short* g, unsigned short* l) {
  __builtin_amdgcn_global_load_lds(
      (const __attribute__((address_space(1))) unsigned int*)g,
      (__attribute__((address_space(3))) unsigned int*)l, 16, 0, 0);
}

// Fused prep: one wave per row, rows [0,M) are x, rows [M,M+N) are protos.
// x:      bf16-cast + ||x||^2 (fp32, pre-rounding)
// protos: expmap0+project -> bf16, ||p||^2, es2 = exp(log_scale)*ln2
__global__ void prep_all(const float* __restrict__ x, const float* __restrict__ pt,
                         const float* __restrict__ ls,
                         unsigned short* __restrict__ xbf, unsigned short* __restrict__ pbf,
                         float* __restrict__ x2, float* __restrict__ y2,
                         float* __restrict__ es2, int M, int N, int D) {
  int row = blockIdx.x * (blockDim.x >> 6) + (threadIdx.x >> 6);
  int lane = threadIdx.x & 63;
  if (row >= M + N) return;
  const bool isX = row < M;
  const int r = isX ? row : row - M;
  const float* src = (isX ? x : pt) + (size_t)r * D;
  f32x4 v = ((const f32x4*)src)[lane];
  float ss = v[0]*v[0] + v[1]*v[1] + v[2]*v[2] + v[3]*v[3];
  #pragma unroll
  for (int off = 32; off >= 1; off >>= 1) ss += __shfl_xor(ss, off);
  float scale = 1.0f;
  float outsq = ss;
  if (!isX) {
    float vn  = sqrtf(ss);
    float vnc = fmaxf(vn, 1e-15f);
    float th  = tanhf(vnc);
    scale = th / vnc;                 // p = scale * v
    float pn = scale * vn;            // ||p||
    if (pn > MAX_NORM) { float pr = MAX_NORM / pn; scale *= pr; pn = MAX_NORM; }
    outsq = pn * pn;
  }
  unsigned short* dst = (isX ? xbf : pbf) + (size_t)r * D + lane * 4;
  unsigned long long pk =
        (unsigned long long)f2bf(v[0]*scale)
      | ((unsigned long long)f2bf(v[1]*scale) << 16)
      | ((unsigned long long)f2bf(v[2]*scale) << 32)
      | ((unsigned long long)f2bf(v[3]*scale) << 48);
  *(unsigned long long*)dst = pk;
  if (lane == 0) {
    if (isX) x2[r] = outsq;
    else { y2[r] = outsq; es2[r] = __expf(ls[r]) * LN2; }
  }
}

// 128x128 tile, 4 waves (2x2), 4x4 fragments of 16x16x32 bf16 MFMA per wave.
// R2-proven loop: BK=64 double-buffer (2 planes of [128][32]), __syncthreads.
// MFMA operands SWAPPED (mfma(B,A)): lane&15 indexes M-dim -> the 4 regs of a
// fragment hit 4 consecutive N columns -> float4 nontemporal stores.
__global__ __launch_bounds__(256, 2)
void hyp_gemm(const unsigned short* __restrict__ xbf,
              const unsigned short* __restrict__ pbf,
              const float* __restrict__ x2, const float* __restrict__ y2,
              const float* __restrict__ es2, float* __restrict__ out,
              int M, int N, int K) {
  __shared__ __align__(16) unsigned short As[2][2][128 * 32];
  __shared__ __align__(16) unsigned short Bs[2][2][128 * 32];
  const int t    = threadIdx.x;
  const int wv   = t >> 6;
  const int lane = t & 63;
  const int wr   = wv >> 1, wc = wv & 1;
  const int frow = lane & 15, kgrp = lane >> 4;
  const int nTM  = M >> 7;

  // XCD-aware swizzle (bijective since gridDim.x % 8 == 0 here)
  int bid = blockIdx.x;
  int swz = ((gridDim.x & 7) == 0) ? ((bid & 7) * (gridDim.x >> 3) + (bid >> 3)) : bid;
  const int tileM = swz % nTM;
  const int tileN = swz / nTM;
  const int gr0 = tileM * 128 + wr * 64;
  const int gc0 = tileN * 128 + wc * 64;
  const int NT  = K >> 6;   // BK=64 steps (K=256 -> 4)

  f32x4 acc[4][4];
  #pragma unroll
  for (int m = 0; m < 4; ++m)
    #pragma unroll
    for (int n = 0; n < 4; ++n) acc[m][n] = (f32x4){0.f, 0.f, 0.f, 0.f};

  // staging: per plane (32 k-elems), per j (64-row half): wave wv covers rows
  // j*64 + wv*16 + (lane>>2), k-elems (lane&3)*8 .. +8  (16 B per lane)
  const int srow  = wv * 16 + (lane >> 2);
  const int skoff = (lane & 3) * 8;
  const unsigned short* gA = xbf + (size_t)(tileM * 128 + srow) * K + skoff;
  const unsigned short* gB = pbf + (size_t)(tileN * 128 + srow) * K + skoff;
  const size_t rskip = (size_t)64 * K;

#define STAGE(b, kt)                                                           \
  {                                                                            \
    _Pragma("unroll")                                                          \
    for (int p = 0; p < 2; ++p) {                                              \
      _Pragma("unroll")                                                        \
      for (int j = 0; j < 2; ++j) {                                            \
        gld16(gA + (size_t)j * rskip + (kt) * 64 + p * 32,                     \
              &As[b][p][(j * 64 + wv * 16) * 32]);                             \
        gld16(gB + (size_t)j * rskip + (kt) * 64 + p * 32,                     \
              &Bs[b][p][(j * 64 + wv * 16) * 32]);                             \
      }                                                                        \
    }                                                                          \
  }

#define COMPUTE(b)                                                             \
  {                                                                            \
    _Pragma("unroll")                                                          \
    for (int p = 0; p < 2; ++p) {                                              \
      bf16x8 af[4], bg[4];                                                     \
      _Pragma("unroll")                                                        \
      for (int m = 0; m < 4; ++m)                                              \
        af[m] = *(const bf16x8*)&As[b][p][(wr * 64 + m * 16 + frow) * 32 + kgrp * 8]; \
      _Pragma("unroll")                                                        \
      for (int n = 0; n < 4; ++n)                                              \
        bg[n] = *(const bf16x8*)&Bs[b][p][(wc * 64 + n * 16 + frow) * 32 + kgrp * 8]; \
      _Pragma("unroll")                                                        \
      for (int m = 0; m < 4; ++m)                                              \
        _Pragma("unroll")                                                      \
        for (int n = 0; n < 4; ++n)                                            \
          acc[m][n] = __builtin_amdgcn_mfma_f32_16x16x32_bf16(bg[n], af[m], acc[m][n], 0, 0, 0); \
    }                                                                          \
  }

  STAGE(0, 0);
  __syncthreads();
  int cur = 0;
  for (int kt = 0; kt < NT; ++kt) {
    if (kt + 1 < NT) STAGE(cur ^ 1, kt + 1);
    COMPUTE(cur);
    __syncthreads();
    cur ^= 1;
  }
#undef STAGE
#undef COMPUTE

  // Swapped C/D layout: element = out[(gr0+m*16+frow)*N + gc0+n*16+kgrp*4+r]
  // -> x2 scalar per (m,frow); y2/es2 f32x4 per (n,kgrp); float4 NT stores.
  // dist = ln((den+t)/(den-t)), t = min(sqrt(num), MAX_NORM*den);
  // out = es*ln2*(log2(den-t) - log2(den+t))
  float x2s[4];
  #pragma unroll
  for (int m = 0; m < 4; ++m) x2s[m] = x2[gr0 + m * 16 + frow];
  #pragma unroll
  for (int n = 0; n < 4; ++n) {
    const int c0 = gc0 + n * 16 + kgrp * 4;
    f32x4 y2v = *(const f32x4*)(y2 + c0);
    f32x4 esv = *(const f32x4*)(es2 + c0);
    #pragma unroll
    for (int m = 0; m < 4; ++m) {
      f32x4 a4 = acc[m][n];
      f32x4 o;
      #pragma unroll
      for (int r = 0; r < 4; ++r) {
        float nxy = -a4[r];
        float x2c = x2s[m];
        float y2c = y2v[r];
        float Bb  = 1.0f - x2c;
        float t1  = fmaf(2.0f, nxy, 1.0f);            // 1 + 2*nxy
        float A   = t1 + y2c;
        float den = fmaxf(fmaf(x2c, y2c, t1), 1e-15f);
        float num = fmaf(A * A, x2c, fmaf((2.0f * A) * Bb, nxy, (Bb * Bb) * y2c));
        float s   = __builtin_amdgcn_sqrtf(fmaxf(num, 0.0f));
        float t2  = fminf(s, MAX_NORM * den);
        o[r] = esv[r] * (__log2f(den - t2) - __log2f(den + t2));
      }
      __builtin_nontemporal_store(o, (f32x4*)&out[(size_t)(gr0 + m * 16 + frow) * N + c0]);
    }
  }
}

extern "C" void kernel_launch(void* const* d_in, const int* in_sizes, int n_in,
                              void* d_out, int out_size, void* d_ws, size_t ws_size,
                              hipStream_t stream) {
  const float* x  = (const float*)d_in[0];
  const float* pt = (const float*)d_in[1];
  const float* ls = (const float*)d_in[2];
  const int Csz = in_sizes[2];
  const int D   = in_sizes[1] / Csz;   // 256
  const int Bsz = in_sizes[0] / D;     // 4096
  const int M = Bsz, N = Csz, K = D;
  float* outp = (float*)d_out;

  char* ws = (char*)d_ws;
  unsigned short* xbf = (unsigned short*)ws; ws += (size_t)M * K * 2;
  unsigned short* pbf = (unsigned short*)ws; ws += (size_t)N * K * 2;
  float* x2  = (float*)ws; ws += (size_t)M * 4;
  float* y2  = (float*)ws; ws += (size_t)N * 4;
  float* es2 = (float*)ws; ws += (size_t)N * 4;

  hipLaunchKernelGGL(prep_all, dim3((M + N + 3) / 4), dim3(256), 0, stream,
                     x, pt, ls, xbf, pbf, x2, y2, es2, M, N, K);
  hipLaunchKernelGGL(hyp_gemm, dim3((M / 128) * (N / 128)), dim3(256), 0, stream,
                     xbf, pbf, x2, y2, es2, outp, M, N, K);
}

// Round 6
// 58.638 us; speedup vs baseline: 1.3838x; 1.3838x over previous
//
#include <hip/hip_runtime.h>
#include <hip/hip_bf16.h>
#include <cstdint>

#define MAX_NORM (1.0f - 1e-5f)
#define LN2 0.69314718056f

typedef __attribute__((ext_vector_type(8))) short bf16x8;
typedef __attribute__((ext_vector_type(4))) float f32x4;

__device__ __forceinline__ unsigned short f2bf(float f) {
  union { float f; unsigned int u; } c; c.f = f;
  unsigned int r = c.u + 0x7fffu + ((c.u >> 16) & 1u);
  return (unsigned short)(r >> 16);
}

__device__ __forceinline__ void gld16(const unsigned short* g, unsigned short* l) {
  __builtin_amdgcn_global_load_lds(
      (const __attribute__((address_space(1))) unsigned int*)g,
      (__attribute__((address_space(3))) unsigned int*)l, 16, 0, 0);
}

// Fused prep: one wave per row, rows [0,M) are x, rows [M,M+N) are protos.
// x:      bf16-cast + ||x||^2 (fp32, pre-rounding)
// protos: expmap0+project -> bf16, ||p||^2, es2 = exp(log_scale)*ln2
__global__ void prep_all(const float* __restrict__ x, const float* __restrict__ pt,
                         const float* __restrict__ ls,
                         unsigned short* __restrict__ xbf, unsigned short* __restrict__ pbf,
                         float* __restrict__ x2, float* __restrict__ y2,
                         float* __restrict__ es2, int M, int N, int D) {
  int row = blockIdx.x * (blockDim.x >> 6) + (threadIdx.x >> 6);
  int lane = threadIdx.x & 63;
  if (row >= M + N) return;
  const bool isX = row < M;
  const int r = isX ? row : row - M;
  const float* src = (isX ? x : pt) + (size_t)r * D;
  f32x4 v = ((const f32x4*)src)[lane];
  float ss = v[0]*v[0] + v[1]*v[1] + v[2]*v[2] + v[3]*v[3];
  #pragma unroll
  for (int off = 32; off >= 1; off >>= 1) ss += __shfl_xor(ss, off);
  float scale = 1.0f;
  float outsq = ss;
  if (!isX) {
    float vn  = sqrtf(ss);
    float vnc = fmaxf(vn, 1e-15f);
    float th  = tanhf(vnc);
    scale = th / vnc;                 // p = scale * v
    float pn = scale * vn;            // ||p||
    if (pn > MAX_NORM) { float pr = MAX_NORM / pn; scale *= pr; pn = MAX_NORM; }
    outsq = pn * pn;
  }
  unsigned short* dst = (isX ? xbf : pbf) + (size_t)r * D + lane * 4;
  unsigned long long pk =
        (unsigned long long)f2bf(v[0]*scale)
      | ((unsigned long long)f2bf(v[1]*scale) << 16)
      | ((unsigned long long)f2bf(v[2]*scale) << 32)
      | ((unsigned long long)f2bf(v[3]*scale) << 48);
  *(unsigned long long*)dst = pk;
  if (lane == 0) {
    if (isX) x2[r] = outsq;
    else { y2[r] = outsq; es2[r] = __expf(ls[r]) * LN2; }
  }
}

// 128x128 tile, 4 waves (2x2), 4x4 fragments of 16x16x32 bf16 MFMA per wave.
// R2-proven loop: BK=64 double-buffer (2 planes of [128][32]), __syncthreads,
// plain stores, NO nontemporal, NO XCD swizzle.
// MFMA operands SWAPPED (mfma(B,A)): lane&15 indexes M-dim -> the 4 regs of a
// fragment are 4 consecutive N columns -> plain float4 stores (16/thread).
__global__ __launch_bounds__(256, 2)
void hyp_gemm(const unsigned short* __restrict__ xbf,
              const unsigned short* __restrict__ pbf,
              const float* __restrict__ x2, const float* __restrict__ y2,
              const float* __restrict__ es2, float* __restrict__ out,
              int M, int N, int K) {
  __shared__ __align__(16) unsigned short As[2][2][128 * 32];
  __shared__ __align__(16) unsigned short Bs[2][2][128 * 32];
  const int t    = threadIdx.x;
  const int wv   = t >> 6;
  const int lane = t & 63;
  const int wr   = wv >> 1, wc = wv & 1;
  const int frow = lane & 15, kgrp = lane >> 4;
  const int nTM  = M >> 7;
  const int tileM = blockIdx.x % nTM;
  const int tileN = blockIdx.x / nTM;
  const int gr0 = tileM * 128 + wr * 64;
  const int gc0 = tileN * 128 + wc * 64;
  const int NT  = K >> 6;   // BK=64 steps (K=256 -> 4)

  f32x4 acc[4][4];
  #pragma unroll
  for (int m = 0; m < 4; ++m)
    #pragma unroll
    for (int n = 0; n < 4; ++n) acc[m][n] = (f32x4){0.f, 0.f, 0.f, 0.f};

  // staging: per plane (32 k-elems), per j (64-row half): wave wv covers rows
  // j*64 + wv*16 + (lane>>2), k-elems (lane&3)*8 .. +8  (16 B per lane)
  const int srow  = wv * 16 + (lane >> 2);
  const int skoff = (lane & 3) * 8;
  const unsigned short* gA = xbf + (size_t)(tileM * 128 + srow) * K + skoff;
  const unsigned short* gB = pbf + (size_t)(tileN * 128 + srow) * K + skoff;
  const size_t rskip = (size_t)64 * K;

#define STAGE(b, kt)                                                           \
  {                                                                            \
    _Pragma("unroll")                                                          \
    for (int p = 0; p < 2; ++p) {                                              \
      _Pragma("unroll")                                                        \
      for (int j = 0; j < 2; ++j) {                                            \
        gld16(gA + (size_t)j * rskip + (kt) * 64 + p * 32,                     \
              &As[b][p][(j * 64 + wv * 16) * 32]);                             \
        gld16(gB + (size_t)j * rskip + (kt) * 64 + p * 32,                     \
              &Bs[b][p][(j * 64 + wv * 16) * 32]);                             \
      }                                                                        \
    }                                                                          \
  }

#define COMPUTE(b)                                                             \
  {                                                                            \
    _Pragma("unroll")                                                          \
    for (int p = 0; p < 2; ++p) {                                              \
      bf16x8 af[4], bg[4];                                                     \
      _Pragma("unroll")                                                        \
      for (int m = 0; m < 4; ++m)                                              \
        af[m] = *(const bf16x8*)&As[b][p][(wr * 64 + m * 16 + frow) * 32 + kgrp * 8]; \
      _Pragma("unroll")                                                        \
      for (int n = 0; n < 4; ++n)                                              \
        bg[n] = *(const bf16x8*)&Bs[b][p][(wc * 64 + n * 16 + frow) * 32 + kgrp * 8]; \
      _Pragma("unroll")                                                        \
      for (int m = 0; m < 4; ++m)                                              \
        _Pragma("unroll")                                                      \
        for (int n = 0; n < 4; ++n)                                            \
          acc[m][n] = __builtin_amdgcn_mfma_f32_16x16x32_bf16(bg[n], af[m], acc[m][n], 0, 0, 0); \
    }                                                                          \
  }

  STAGE(0, 0);
  __syncthreads();
  int cur = 0;
  for (int kt = 0; kt < NT; ++kt) {
    if (kt + 1 < NT) STAGE(cur ^ 1, kt + 1);
    COMPUTE(cur);
    __syncthreads();
    cur ^= 1;
  }
#undef STAGE
#undef COMPUTE

  // Swapped C/D layout: element = out[(gr0+m*16+frow)*N + gc0+n*16+kgrp*4+r]
  // -> x2 scalar per (m,frow); y2/es2 f32x4 per (n,kgrp); plain float4 stores.
  // dist = ln((den+t)/(den-t)), t = min(sqrt(num), MAX_NORM*den);
  // out = es*ln2*(log2(den-t) - log2(den+t))
  float x2s[4];
  #pragma unroll
  for (int m = 0; m < 4; ++m) x2s[m] = x2[gr0 + m * 16 + frow];
  #pragma unroll
  for (int n = 0; n < 4; ++n) {
    const int c0 = gc0 + n * 16 + kgrp * 4;
    f32x4 y2v = *(const f32x4*)(y2 + c0);
    f32x4 esv = *(const f32x4*)(es2 + c0);
    #pragma unroll
    for (int m = 0; m < 4; ++m) {
      f32x4 a4 = acc[m][n];
      f32x4 o;
      #pragma unroll
      for (int r = 0; r < 4; ++r) {
        float nxy = -a4[r];
        float x2c = x2s[m];
        float y2c = y2v[r];
        float Bb  = 1.0f - x2c;
        float t1  = fmaf(2.0f, nxy, 1.0f);            // 1 + 2*nxy
        float A   = t1 + y2c;
        float den = fmaxf(fmaf(x2c, y2c, t1), 1e-15f);
        float num = fmaf(A * A, x2c, fmaf((2.0f * A) * Bb, nxy, (Bb * Bb) * y2c));
        float s   = __builtin_amdgcn_sqrtf(fmaxf(num, 0.0f));
        float t2  = fminf(s, MAX_NORM * den);
        o[r] = esv[r] * (__log2f(den - t2) - __log2f(den + t2));
      }
      *(f32x4*)&out[(size_t)(gr0 + m * 16 + frow) * N + c0] = o;
    }
  }
}

extern "C" void kernel_launch(void* const* d_in, const int* in_sizes, int n_in,
                              void* d_out, int out_size, void* d_ws, size_t ws_size,
                              hipStream_t stream) {
  const float* x  = (const float*)d_in[0];
  const float* pt = (const float*)d_in[1];
  const float* ls = (const float*)d_in[2];
  const int Csz = in_sizes[2];
  const int D   = in_sizes[1] / Csz;   // 256
  const int Bsz = in_sizes[0] / D;     // 4096
  const int M = Bsz, N = Csz, K = D;
  float* outp = (float*)d_out;

  char* ws = (char*)d_ws;
  unsigned short* xbf = (unsigned short*)ws; ws += (size_t)M * K * 2;
  unsigned short* pbf = (unsigned short*)ws; ws += (size_t)N * K * 2;
  float* x2  = (float*)ws; ws += (size_t)M * 4;
  float* y2  = (float*)ws; ws += (size_t)N * 4;
  float* es2 = (float*)ws; ws += (size_t)N * 4;

  hipLaunchKernelGGL(prep_all, dim3((M + N + 3) / 4), dim3(256), 0, stream,
                     x, pt, ls, xbf, pbf, x2, y2, es2, M, N, K);
  hipLaunchKernelGGL(hyp_gemm, dim3((M / 128) * (N / 128)), dim3(256), 0, stream,
                     xbf, pbf, x2, y2, es2, outp, M, N, K);
}

// Round 7
// 55.583 us; speedup vs baseline: 1.4598x; 1.0550x over previous
//
#include <hip/hip_runtime.h>
#include <hip/hip_bf16.h>
#include <cstdint>

#define MAX_NORM (1.0f - 1e-5f)
#define LN2 0.69314718056f
// w-clamp equivalent of norm <= MAX_NORM: w_max = (1+MAX_NORM)/(1-MAX_NORM)
#define WMAX ((1.0f + MAX_NORM) / (1.0f - MAX_NORM))

typedef __attribute__((ext_vector_type(8))) short bf16x8;
typedef __attribute__((ext_vector_type(4))) float f32x4;

__device__ __forceinline__ unsigned short f2bf(float f) {
  union { float f; unsigned int u; } c; c.f = f;
  unsigned int r = c.u + 0x7fffu + ((c.u >> 16) & 1u);
  return (unsigned short)(r >> 16);
}

__device__ __forceinline__ void gld16(const unsigned short* g, unsigned short* l) {
  __builtin_amdgcn_global_load_lds(
      (const __attribute__((address_space(1))) unsigned int*)g,
      (__attribute__((address_space(3))) unsigned int*)l, 16, 0, 0);
}

// Fused prep: one wave per row, rows [0,M) are x, rows [M,M+N) are protos.
// x:      bf16-cast; x2 = ||x||^2; fx = 2/(1-x2)
// protos: expmap0+project -> bf16; gy = 1/(1-y2); hy = gy*y2; es2 = -exp(ls)*ln2
__global__ void prep_all(const float* __restrict__ x, const float* __restrict__ pt,
                         const float* __restrict__ ls,
                         unsigned short* __restrict__ xbf, unsigned short* __restrict__ pbf,
                         float* __restrict__ x2, float* __restrict__ fx,
                         float* __restrict__ gy, float* __restrict__ hy,
                         float* __restrict__ es2, int M, int N, int D) {
  int row = blockIdx.x * (blockDim.x >> 6) + (threadIdx.x >> 6);
  int lane = threadIdx.x & 63;
  if (row >= M + N) return;
  const bool isX = row < M;
  const int r = isX ? row : row - M;
  const float* src = (isX ? x : pt) + (size_t)r * D;
  f32x4 v = ((const f32x4*)src)[lane];
  float ss = v[0]*v[0] + v[1]*v[1] + v[2]*v[2] + v[3]*v[3];
  #pragma unroll
  for (int off = 32; off >= 1; off >>= 1) ss += __shfl_xor(ss, off);
  float scale = 1.0f;
  float outsq = ss;
  if (!isX) {
    float vn  = sqrtf(ss);
    float vnc = fmaxf(vn, 1e-15f);
    float th  = tanhf(vnc);
    scale = th / vnc;                 // p = scale * v
    float pn = scale * vn;            // ||p||
    if (pn > MAX_NORM) { float pr = MAX_NORM / pn; scale *= pr; pn = MAX_NORM; }
    outsq = pn * pn;
  }
  unsigned short* dst = (isX ? xbf : pbf) + (size_t)r * D + lane * 4;
  unsigned long long pk =
        (unsigned long long)f2bf(v[0]*scale)
      | ((unsigned long long)f2bf(v[1]*scale) << 16)
      | ((unsigned long long)f2bf(v[2]*scale) << 32)
      | ((unsigned long long)f2bf(v[3]*scale) << 48);
  *(unsigned long long*)dst = pk;
  if (lane == 0) {
    if (isX) {
      x2[r] = outsq;
      fx[r] = 2.0f / (1.0f - outsq);
    } else {
      float g = 1.0f / (1.0f - outsq);
      gy[r]  = g;
      hy[r]  = g * outsq;
      es2[r] = -__expf(ls[r]) * LN2;
    }
  }
}

// 128x128 tile, 4 waves (2x2), 4x4 fragments of 16x16x32 bf16 MFMA per wave.
// R6-proven loop: BK=64 double-buffer (2 planes of [128][32]), __syncthreads,
// plain stores. MFMA operands SWAPPED (mfma(B,A)): lane&15 indexes M-dim ->
// fragment regs are 4 consecutive N columns -> plain float4 stores.
// Epilogue via Poincare identity: d = arccosh(1 + 2||x-y||^2/((1-x2)(1-y2)))
//   u = 1 + fx*(gy*(x2 - 2xy) + hy);  d = ln(u + sqrt(u^2-1));  out = es2*log2(w)
__global__ __launch_bounds__(256, 2)
void hyp_gemm(const unsigned short* __restrict__ xbf,
              const unsigned short* __restrict__ pbf,
              const float* __restrict__ x2, const float* __restrict__ fx,
              const float* __restrict__ gy, const float* __restrict__ hy,
              const float* __restrict__ es2, float* __restrict__ out,
              int M, int N, int K) {
  __shared__ __align__(16) unsigned short As[2][2][128 * 32];
  __shared__ __align__(16) unsigned short Bs[2][2][128 * 32];
  const int t    = threadIdx.x;
  const int wv   = t >> 6;
  const int lane = t & 63;
  const int wr   = wv >> 1, wc = wv & 1;
  const int frow = lane & 15, kgrp = lane >> 4;
  const int nTM  = M >> 7;
  const int tileM = blockIdx.x % nTM;
  const int tileN = blockIdx.x / nTM;
  const int gr0 = tileM * 128 + wr * 64;
  const int gc0 = tileN * 128 + wc * 64;
  const int NT  = K >> 6;   // BK=64 steps (K=256 -> 4)

  f32x4 acc[4][4];
  #pragma unroll
  for (int m = 0; m < 4; ++m)
    #pragma unroll
    for (int n = 0; n < 4; ++n) acc[m][n] = (f32x4){0.f, 0.f, 0.f, 0.f};

  // staging: per plane (32 k-elems), per j (64-row half): wave wv covers rows
  // j*64 + wv*16 + (lane>>2), k-elems (lane&3)*8 .. +8  (16 B per lane)
  const int srow  = wv * 16 + (lane >> 2);
  const int skoff = (lane & 3) * 8;
  const unsigned short* gA = xbf + (size_t)(tileM * 128 + srow) * K + skoff;
  const unsigned short* gB = pbf + (size_t)(tileN * 128 + srow) * K + skoff;
  const size_t rskip = (size_t)64 * K;

#define STAGE(b, kt)                                                           \
  {                                                                            \
    _Pragma("unroll")                                                          \
    for (int p = 0; p < 2; ++p) {                                              \
      _Pragma("unroll")                                                        \
      for (int j = 0; j < 2; ++j) {                                            \
        gld16(gA + (size_t)j * rskip + (kt) * 64 + p * 32,                     \
              &As[b][p][(j * 64 + wv * 16) * 32]);                             \
        gld16(gB + (size_t)j * rskip + (kt) * 64 + p * 32,                     \
              &Bs[b][p][(j * 64 + wv * 16) * 32]);                             \
      }                                                                        \
    }                                                                          \
  }

#define COMPUTE(b)                                                             \
  {                                                                            \
    _Pragma("unroll")                                                          \
    for (int p = 0; p < 2; ++p) {                                              \
      bf16x8 af[4], bg[4];                                                     \
      _Pragma("unroll")                                                        \
      for (int m = 0; m < 4; ++m)                                              \
        af[m] = *(const bf16x8*)&As[b][p][(wr * 64 + m * 16 + frow) * 32 + kgrp * 8]; \
      _Pragma("unroll")                                                        \
      for (int n = 0; n < 4; ++n)                                              \
        bg[n] = *(const bf16x8*)&Bs[b][p][(wc * 64 + n * 16 + frow) * 32 + kgrp * 8]; \
      _Pragma("unroll")                                                        \
      for (int m = 0; m < 4; ++m)                                              \
        _Pragma("unroll")                                                      \
        for (int n = 0; n < 4; ++n)                                            \
          acc[m][n] = __builtin_amdgcn_mfma_f32_16x16x32_bf16(bg[n], af[m], acc[m][n], 0, 0, 0); \
    }                                                                          \
  }

  STAGE(0, 0);
  __syncthreads();
  int cur = 0;
  for (int kt = 0; kt < NT; ++kt) {
    if (kt + 1 < NT) STAGE(cur ^ 1, kt + 1);
    COMPUTE(cur);
    __syncthreads();
    cur ^= 1;
  }
#undef STAGE
#undef COMPUTE

  // Swapped C/D layout: element = out[(gr0+m*16+frow)*N + gc0+n*16+kgrp*4+r]
  float x2s[4], fxs[4];
  #pragma unroll
  for (int m = 0; m < 4; ++m) {
    x2s[m] = x2[gr0 + m * 16 + frow];
    fxs[m] = fx[gr0 + m * 16 + frow];
  }
  #pragma unroll
  for (int n = 0; n < 4; ++n) {
    const int c0 = gc0 + n * 16 + kgrp * 4;
    f32x4 gv = *(const f32x4*)(gy  + c0);
    f32x4 hv = *(const f32x4*)(hy  + c0);
    f32x4 ev = *(const f32x4*)(es2 + c0);
    #pragma unroll
    for (int m = 0; m < 4; ++m) {
      f32x4 a4 = acc[m][n];
      f32x4 o;
      #pragma unroll
      for (int r = 0; r < 4; ++r) {
        float xy = a4[r];
        float u  = fmaf(fxs[m], fmaf(gv[r], fmaf(-2.0f, xy, x2s[m]), hv[r]), 1.0f);
        float t2 = fmaxf(fmaf(u, u, -1.0f), 0.0f);
        float w  = u + __builtin_amdgcn_sqrtf(t2);
        w = fminf(w, WMAX);
        o[r] = ev[r] * __log2f(w);
      }
      *(f32x4*)&out[(size_t)(gr0 + m * 16 + frow) * N + c0] = o;
    }
  }
}

extern "C" void kernel_launch(void* const* d_in, const int* in_sizes, int n_in,
                              void* d_out, int out_size, void* d_ws, size_t ws_size,
                              hipStream_t stream) {
  const float* x  = (const float*)d_in[0];
  const float* pt = (const float*)d_in[1];
  const float* ls = (const float*)d_in[2];
  const int Csz = in_sizes[2];
  const int D   = in_sizes[1] / Csz;   // 256
  const int Bsz = in_sizes[0] / D;     // 4096
  const int M = Bsz, N = Csz, K = D;
  float* outp = (float*)d_out;

  char* ws = (char*)d_ws;
  unsigned short* xbf = (unsigned short*)ws; ws += (size_t)M * K * 2;
  unsigned short* pbf = (unsigned short*)ws; ws += (size_t)N * K * 2;
  float* x2  = (float*)ws; ws += (size_t)M * 4;
  float* fx  = (float*)ws; ws += (size_t)M * 4;
  float* gy  = (float*)ws; ws += (size_t)N * 4;
  float* hy  = (float*)ws; ws += (size_t)N * 4;
  float* es2 = (float*)ws; ws += (size_t)N * 4;

  hipLaunchKernelGGL(prep_all, dim3((M + N + 3) / 4), dim3(256), 0, stream,
                     x, pt, ls, xbf, pbf, x2, fx, gy, hy, es2, M, N, K);
  hipLaunchKernelGGL(hyp_gemm, dim3((M / 128) * (N / 128)), dim3(256), 0, stream,
                     xbf, pbf, x2, fx, gy, hy, es2, outp, M, N, K);
}